// Round 3
// baseline (442.042 us; speedup 1.0000x reference)
//
#include <hip/hip_runtime.h>
#include <stdint.h>

#define M_DIM 8192
#define N_DIM 4096
#define K_DIM 4096

typedef __attribute__((ext_vector_type(4))) int int32x4;

// --- Fused prep kernel ---
// Blocks [0, 2048):   per-row absmax quantize X fp32 -> i8. ONE WAVE PER ROW:
//   no cross-wave barrier, row held in registers (64 VGPRs), loads/stores
//   perfectly coalesced (lane + 64*j float4 indexing).
// Blocks [2048, 3072): W fp32 -> sign(W) i8 (+1/-1), grid-strided map.
#define QUANT_BLOCKS 2048
#define SIGN_BLOCKS  1024
#define SIGN_THREADS (SIGN_BLOCKS * 256)   // 262144 threads, 4 int4 each = 16 MB

__global__ __launch_bounds__(256) void prep_kernel(const float* __restrict__ x,
                                                   const float* __restrict__ w,
                                                   signed char* __restrict__ xq,
                                                   signed char* __restrict__ wq,
                                                   float* __restrict__ scales) {
  const int bid = blockIdx.x;
  const int t = threadIdx.x;
  if (bid < QUANT_BLOCKS) {
    const int wave = t >> 6, lane = t & 63;
    const int row = bid * 4 + wave;
    const float4* xr = (const float4*)(x + (size_t)row * K_DIM);
    float4 v[16];
    float amax = 0.f;
#pragma unroll
    for (int j = 0; j < 16; j++) {
      v[j] = xr[lane + 64 * j];
      amax = fmaxf(amax, fmaxf(fmaxf(fabsf(v[j].x), fabsf(v[j].y)),
                               fmaxf(fabsf(v[j].z), fabsf(v[j].w))));
    }
#pragma unroll
    for (int off = 32; off > 0; off >>= 1)
      amax = fmaxf(amax, __shfl_xor(amax, off, 64));
    amax = fmaxf(amax, 1e-30f);
    const float rsc = 127.0f / amax;
    if (lane == 0) scales[row] = amax / 127.0f;
    int* qr = (int*)(xq + (size_t)row * K_DIM);
#pragma unroll
    for (int j = 0; j < 16; j++) {
      int q0 = __float2int_rn(v[j].x * rsc);
      int q1 = __float2int_rn(v[j].y * rsc);
      int q2 = __float2int_rn(v[j].z * rsc);
      int q3 = __float2int_rn(v[j].w * rsc);
      qr[lane + 64 * j] = (q0 & 255) | ((q1 & 255) << 8) | ((q2 & 255) << 16) | (q3 << 24);
    }
  } else {
    const int idx0 = (bid - QUANT_BLOCKS) * 256 + t;  // int4 output index
    const float4* wf = (const float4*)w;
    int4* o = (int4*)wq;
#pragma unroll
    for (int k = 0; k < 4; k++) {
      const int idx = idx0 + k * SIGN_THREADS;
      int4 pk;
      int* pi = (int*)&pk;
#pragma unroll
      for (int j = 0; j < 4; j++) {
        float4 a = wf[(size_t)idx * 4 + j];
        unsigned b0 = a.x >= 0.f ? 0x01u : 0xFFu;
        unsigned b1 = a.y >= 0.f ? 0x01u : 0xFFu;
        unsigned b2 = a.z >= 0.f ? 0x01u : 0xFFu;
        unsigned b3 = a.w >= 0.f ? 0x01u : 0xFFu;
        pi[j] = (int)(b0 | (b1 << 8) | (b2 << 16) | (b3 << 24));
      }
      o[idx] = pk;
    }
  }
}

// Async global->LDS, 16 bytes/lane. LDS dest = wave-uniform base + lane*16.
__device__ __forceinline__ void async16(const signed char* g, signed char* l) {
  __builtin_amdgcn_global_load_lds((const __attribute__((address_space(1))) void*)g,
                                   (__attribute__((address_space(3))) void*)l, 16, 0, 0);
}

// --- GEMM: C[M,N] = (Xq[M,K] i8 . Wq[N,K]^T i8) * s_row + bias, exact i32 acc.
// m97 skeleton: 128x128 tile, BK=64, 4 waves 2x2, 4x4 mfma_i32_16x16x64_i8 per wave.
// Unchanged from round 2: 199 us, MfmaUtil ~30% -- the known structural plateau.
__global__ __launch_bounds__(256) void gemm_i8_kernel(
    const signed char* __restrict__ A,
    const signed char* __restrict__ B,
    const float* __restrict__ scales,
    const float* __restrict__ bias,
    float* __restrict__ C) {
  __shared__ signed char la[128 * 64];  // 8 KB
  __shared__ signed char lb[128 * 64];  // 8 KB

  const int tid  = threadIdx.x;
  const int wave = tid >> 6;
  const int lane = tid & 63;
  const int wm = wave >> 1, wn = wave & 1;
  const int qd = lane >> 4, l16 = lane & 15;
  const long m0 = (long)blockIdx.y * 128;
  const long n0 = (long)blockIdx.x * 128;

  const int ch0 = wave * 128 + lane;
  const int ch1 = ch0 + 64;
  const signed char* ga0 = A + (m0 + (ch0 >> 2)) * K_DIM + (ch0 & 3) * 16;
  const signed char* ga1 = A + (m0 + (ch1 >> 2)) * K_DIM + (ch1 & 3) * 16;
  const signed char* gb0 = B + (n0 + (ch0 >> 2)) * K_DIM + (ch0 & 3) * 16;
  const signed char* gb1 = B + (n0 + (ch1 >> 2)) * K_DIM + (ch1 & 3) * 16;
  signed char* la0 = &la[(wave * 128) * 16];
  signed char* la1 = &la[(wave * 128 + 64) * 16];
  signed char* lb0 = &lb[(wave * 128) * 16];
  signed char* lb1 = &lb[(wave * 128 + 64) * 16];

  const int32x4* pa[4];
  const int32x4* pb[4];
#pragma unroll
  for (int t = 0; t < 4; t++) {
    pa[t] = (const int32x4*)&la[(wm * 64 + t * 16 + l16) * 64 + qd * 16];
    pb[t] = (const int32x4*)&lb[(wn * 64 + t * 16 + l16) * 64 + qd * 16];
  }

  int32x4 acc[4][4];
#pragma unroll
  for (int i = 0; i < 4; i++)
#pragma unroll
    for (int j = 0; j < 4; j++)
      acc[i][j] = (int32x4){0, 0, 0, 0};

  for (int k0 = 0; k0 < K_DIM; k0 += 64) {
    async16(ga0 + k0, la0);
    async16(ga1 + k0, la1);
    async16(gb0 + k0, lb0);
    async16(gb1 + k0, lb1);
    __syncthreads();

    int32x4 af[4], bf[4];
#pragma unroll
    for (int t = 0; t < 4; t++) { af[t] = *pa[t]; bf[t] = *pb[t]; }
#pragma unroll
    for (int i = 0; i < 4; i++)
#pragma unroll
      for (int j = 0; j < 4; j++)
        acc[i][j] = __builtin_amdgcn_mfma_i32_16x16x64_i8(af[i], bf[j], acc[i][j], 0, 0, 0);

    __syncthreads();
  }

  const long row0 = m0 + wm * 64 + qd * 4;
  const long col0 = n0 + wn * 64 + l16;
#pragma unroll
  for (int tj = 0; tj < 4; tj++) {
    float bv = bias[col0 + tj * 16];
#pragma unroll
    for (int ti = 0; ti < 4; ti++) {
      long r = row0 + ti * 16;
      float4 sv = *(const float4*)&scales[r];
      const float* s = &sv.x;
#pragma unroll
      for (int i = 0; i < 4; i++) {
        C[(r + i) * N_DIM + col0 + tj * 16] = (float)acc[ti][tj][i] * s[i] + bv;
      }
    }
  }
}

extern "C" void kernel_launch(void* const* d_in, const int* in_sizes, int n_in,
                              void* d_out, int out_size, void* d_ws, size_t ws_size,
                              hipStream_t stream) {
  const float* x    = (const float*)d_in[0];   // [8192, 4096] fp32
  const float* w    = (const float*)d_in[1];   // [4096, 4096] fp32
  const float* bias = (const float*)d_in[2];   // [4096] fp32
  float* out = (float*)d_out;                  // [8192, 4096] fp32

  // workspace: X i8 (32 MB) | W sign i8 (16 MB) | row scales (32 KB)
  signed char* xq = (signed char*)d_ws;
  signed char* wq = xq + (size_t)M_DIM * K_DIM;
  float* scales   = (float*)(wq + (size_t)N_DIM * K_DIM);

  prep_kernel<<<QUANT_BLOCKS + SIGN_BLOCKS, 256, 0, stream>>>(x, w, xq, wq, scales);

  dim3 grid(N_DIM / 128, M_DIM / 128);  // (32, 64)
  gemm_i8_kernel<<<grid, 256, 0, stream>>>(xq, wq, scales, bias, out);
}

// Round 4
// 403.269 us; speedup vs baseline: 1.0961x; 1.0961x over previous
//
#include <hip/hip_runtime.h>
#include <stdint.h>

#define M_DIM 8192
#define N_DIM 4096
#define K_DIM 4096

typedef __attribute__((ext_vector_type(4))) int int32x4;

// --- Fused prep kernel (unchanged from round 3) ---
#define QUANT_BLOCKS 2048
#define SIGN_BLOCKS  1024
#define SIGN_THREADS (SIGN_BLOCKS * 256)

__global__ __launch_bounds__(256) void prep_kernel(const float* __restrict__ x,
                                                   const float* __restrict__ w,
                                                   signed char* __restrict__ xq,
                                                   signed char* __restrict__ wq,
                                                   float* __restrict__ scales) {
  const int bid = blockIdx.x;
  const int t = threadIdx.x;
  if (bid < QUANT_BLOCKS) {
    const int wave = t >> 6, lane = t & 63;
    const int row = bid * 4 + wave;
    const float4* xr = (const float4*)(x + (size_t)row * K_DIM);
    float4 v[16];
    float amax = 0.f;
#pragma unroll
    for (int j = 0; j < 16; j++) {
      v[j] = xr[lane + 64 * j];
      amax = fmaxf(amax, fmaxf(fmaxf(fabsf(v[j].x), fabsf(v[j].y)),
                               fmaxf(fabsf(v[j].z), fabsf(v[j].w))));
    }
#pragma unroll
    for (int off = 32; off > 0; off >>= 1)
      amax = fmaxf(amax, __shfl_xor(amax, off, 64));
    amax = fmaxf(amax, 1e-30f);
    const float rsc = 127.0f / amax;
    if (lane == 0) scales[row] = amax / 127.0f;
    int* qr = (int*)(xq + (size_t)row * K_DIM);
#pragma unroll
    for (int j = 0; j < 16; j++) {
      int q0 = __float2int_rn(v[j].x * rsc);
      int q1 = __float2int_rn(v[j].y * rsc);
      int q2 = __float2int_rn(v[j].z * rsc);
      int q3 = __float2int_rn(v[j].w * rsc);
      qr[lane + 64 * j] = (q0 & 255) | ((q1 & 255) << 8) | ((q2 & 255) << 16) | (q3 << 24);
    }
  } else {
    const int idx0 = (bid - QUANT_BLOCKS) * 256 + t;
    const float4* wf = (const float4*)w;
    int4* o = (int4*)wq;
#pragma unroll
    for (int k = 0; k < 4; k++) {
      const int idx = idx0 + k * SIGN_THREADS;
      int4 pk;
      int* pi = (int*)&pk;
#pragma unroll
      for (int j = 0; j < 4; j++) {
        float4 a = wf[(size_t)idx * 4 + j];
        unsigned b0 = a.x >= 0.f ? 0x01u : 0xFFu;
        unsigned b1 = a.y >= 0.f ? 0x01u : 0xFFu;
        unsigned b2 = a.z >= 0.f ? 0x01u : 0xFFu;
        unsigned b3 = a.w >= 0.f ? 0x01u : 0xFFu;
        pi[j] = (int)(b0 | (b1 << 8) | (b2 << 16) | (b3 << 24));
      }
      o[idx] = pk;
    }
  }
}

// Async global->LDS, 16 bytes/lane. LDS dest = wave-uniform base + lane*16;
// the GLOBAL source is per-lane -> we use it to implement an XOR-swizzled
// LDS layout without touching the (fixed) LDS destination pattern.
__device__ __forceinline__ void async16(const signed char* g, signed char* l) {
  __builtin_amdgcn_global_load_lds((const __attribute__((address_space(1))) void*)g,
                                   (__attribute__((address_space(3))) void*)l, 16, 0, 0);
}

// --- GEMM: C[M,N] = (Xq i8 . Wq^T i8) * s_row + bias, exact i32 acc.
// Round-4 changes vs round-3:
//  * BK=128 bytes (32 KB LDS total; occupancy stays 4 blocks/CU, VGPR-limited)
//    -> 32 barrier-drains instead of 64, 32 MFMA/wave per barrier (AITER ratio).
//  * XOR swizzle: row r's k-piece p (16B) lives at LDS sub (p ^ (r&7)).
//    Read banks spread over 8 quads (2-way = free, m136) vs 2 quads before.
__global__ __launch_bounds__(256) void gemm_i8_kernel(
    const signed char* __restrict__ A,
    const signed char* __restrict__ B,
    const float* __restrict__ scales,
    const float* __restrict__ bias,
    float* __restrict__ C) {
  __shared__ signed char la[128 * 128];  // 16 KB: [128 rows][128B], 8 pieces/row
  __shared__ signed char lb[128 * 128];  // 16 KB

  const int tid  = threadIdx.x;
  const int wave = tid >> 6;
  const int lane = tid & 63;
  const int wm = wave >> 1, wn = wave & 1;
  const int qd = lane >> 4, l16 = lane & 15;
  const long m0 = (long)blockIdx.y * 128;
  const long n0 = (long)blockIdx.x * 128;

  // staging: 1024 chunks x 16B per matrix per tile; 256 lanes -> 4 issues each.
  // chunk c = q*256 + wave*64 + lane: row r = c>>3, sub s = c&7.
  // global source piece = s ^ (r&7)  (swizzle); r&7 == (lane>>3)&7, s == lane&7.
  const signed char* gA[4];
  const signed char* gB[4];
  signed char* lA[4];
  signed char* lB[4];
#pragma unroll
  for (int q = 0; q < 4; q++) {
    const int c = q * 256 + wave * 64 + lane;
    const int r = c >> 3, s = c & 7;
    const int off = (s ^ (r & 7)) * 16;
    gA[q] = A + (m0 + r) * K_DIM + off;
    gB[q] = B + (n0 + r) * K_DIM + off;
    lA[q] = &la[(q * 256 + wave * 64) * 16];
    lB[q] = &lb[(q * 256 + wave * 64) * 16];
  }

  // fragment pointers: lane (qd,l16) of tile t, kstep kk reads row
  // r = w*64 + t*16 + l16, global piece p = kk*4 + qd, LDS sub = p ^ (l16&7)
  // (r&7 == l16&7 since w*64, t*16 are multiples of 8/16).
  const int swz = l16 & 7;
  const int32x4* pa[4][2];
  const int32x4* pb[4][2];
#pragma unroll
  for (int t = 0; t < 4; t++) {
#pragma unroll
    for (int kk = 0; kk < 2; kk++) {
      pa[t][kk] = (const int32x4*)&la[(wm * 64 + t * 16 + l16) * 128 + ((kk * 4 + qd) ^ swz) * 16];
      pb[t][kk] = (const int32x4*)&lb[(wn * 64 + t * 16 + l16) * 128 + ((kk * 4 + qd) ^ swz) * 16];
    }
  }

  int32x4 acc[4][4];
#pragma unroll
  for (int i = 0; i < 4; i++)
#pragma unroll
    for (int j = 0; j < 4; j++)
      acc[i][j] = (int32x4){0, 0, 0, 0};

  for (int k0 = 0; k0 < K_DIM; k0 += 128) {
#pragma unroll
    for (int q = 0; q < 4; q++) {
      async16(gA[q] + k0, lA[q]);
      async16(gB[q] + k0, lB[q]);
    }
    __syncthreads();  // vmcnt(0) drain (32 of these now, was 64)

#pragma unroll
    for (int kk = 0; kk < 2; kk++) {
      int32x4 af[4], bf[4];
#pragma unroll
      for (int t = 0; t < 4; t++) { af[t] = *pa[t][kk]; bf[t] = *pb[t][kk]; }
#pragma unroll
      for (int i = 0; i < 4; i++)
#pragma unroll
        for (int j = 0; j < 4; j++)
          acc[i][j] = __builtin_amdgcn_mfma_i32_16x16x64_i8(af[i], bf[j], acc[i][j], 0, 0, 0);
    }

    __syncthreads();  // reads done before next stage overwrites
  }

  // epilogue: C/D layout col=lane&15, row=(lane>>4)*4+reg (shape-determined)
  const long row0 = m0 + wm * 64 + qd * 4;
  const long col0 = n0 + wn * 64 + l16;
#pragma unroll
  for (int tj = 0; tj < 4; tj++) {
    float bv = bias[col0 + tj * 16];
#pragma unroll
    for (int ti = 0; ti < 4; ti++) {
      long r = row0 + ti * 16;
      float4 sv = *(const float4*)&scales[r];
      const float* s = &sv.x;
#pragma unroll
      for (int i = 0; i < 4; i++) {
        C[(r + i) * N_DIM + col0 + tj * 16] = (float)acc[ti][tj][i] * s[i] + bv;
      }
    }
  }
}

extern "C" void kernel_launch(void* const* d_in, const int* in_sizes, int n_in,
                              void* d_out, int out_size, void* d_ws, size_t ws_size,
                              hipStream_t stream) {
  const float* x    = (const float*)d_in[0];   // [8192, 4096] fp32
  const float* w    = (const float*)d_in[1];   // [4096, 4096] fp32
  const float* bias = (const float*)d_in[2];   // [4096] fp32
  float* out = (float*)d_out;                  // [8192, 4096] fp32

  // workspace: X i8 (32 MB) | W sign i8 (16 MB) | row scales (32 KB)
  signed char* xq = (signed char*)d_ws;
  signed char* wq = xq + (size_t)M_DIM * K_DIM;
  float* scales   = (float*)(wq + (size_t)N_DIM * K_DIM);

  prep_kernel<<<QUANT_BLOCKS + SIGN_BLOCKS, 256, 0, stream>>>(x, w, xq, wq, scales);

  dim3 grid(N_DIM / 128, M_DIM / 128);  // (32, 64)
  gemm_i8_kernel<<<grid, 256, 0, stream>>>(xq, wq, scales, bias, out);
}